// Round 1
// baseline (2265.999 us; speedup 1.0000x reference)
//
#include <hip/hip_runtime.h>
#include <hip/hip_bf16.h>
#include <math.h>

#define Bdim 16
#define Tdim 200
#define Pdim 100
#define EMB  100
#define Ddim 300
#define SKILL 30
#define Qdim 50
#define OUTD 50

// d_out layout (floats), concatenated in reference return order:
// res [B,T,50], res2 [B,T,30], kc_mask [B,T,30], attn [B,T,P,1]
#define OFF_RES   0
#define OFF_RES2  (Bdim*Tdim*OUTD)              // 160000
#define OFF_KC    (OFF_RES2 + Bdim*Tdim*SKILL)  // 256000
#define OFF_ATTN  (OFF_KC + Bdim*Tdim*SKILL)    // 352000

#define MBLK 32
#define TPB_A 320

// ---------------------------------------------------------------------------
// Kernel A: raw attention scores.
// score[m] = tanh(full_embed[m] @ W_trans + b_trans) @ W_att + b_att
// full_embed[m] = [nodes[i0] | nodes[i2] | paths[i1]]  (concat order!)
// One block = 32 rows staged in LDS; 320 threads = one output column each,
// 32 fp32 accumulators; per-column tanh + W_att partial, wave-shuffle reduce.
// ---------------------------------------------------------------------------
__global__ __launch_bounds__(TPB_A) void score_kernel(
    const int*   __restrict__ c2v,
    const float* __restrict__ en,
    const float* __restrict__ ep,
    const float* __restrict__ Wt,
    const float* __restrict__ bt,
    const float* __restrict__ Wa,
    const float* __restrict__ ba,
    float* __restrict__ scores)
{
    __shared__ __align__(16) float e_lds[MBLK][Ddim];
    __shared__ int   idx_lds[MBLK * 3];
    __shared__ float ctx_lds[5][MBLK];

    const int tid = threadIdx.x;
    const int m0  = blockIdx.x * MBLK;

    if (tid < MBLK * 3) idx_lds[tid] = c2v[(size_t)m0 * 3 + tid];
    __syncthreads();

    // Stage 32 rows x 300 floats as float4 (each 100-float segment = 25 float4s)
    for (int pos = tid; pos < MBLK * 75; pos += TPB_A) {
        int r  = pos / 75, q = pos - r * 75;
        int seg = q / 25, qq = q - seg * 25;
        int i0 = idx_lds[r * 3 + 0];
        int i1 = idx_lds[r * 3 + 1];
        int i2 = idx_lds[r * 3 + 2];
        const float* src;
        if (seg == 0)      src = en + (size_t)i0 * EMB;   // start
        else if (seg == 1) src = en + (size_t)i2 * EMB;   // end
        else               src = ep + (size_t)i1 * EMB;   // path
        float4 v = ((const float4*)src)[qq];
        *(float4*)&e_lds[r][seg * 100 + qq * 4] = v;
    }
    __syncthreads();

    const int j = tid;  // output column, 300 active of 320
    float acc[MBLK];
    #pragma unroll
    for (int r = 0; r < MBLK; ++r) acc[r] = 0.f;

    if (j < Ddim) {
        const float* Wcol = Wt + j;
        for (int k = 0; k < Ddim; k += 4) {
            float w0 = Wcol[(size_t)(k + 0) * Ddim];
            float w1 = Wcol[(size_t)(k + 1) * Ddim];
            float w2 = Wcol[(size_t)(k + 2) * Ddim];
            float w3 = Wcol[(size_t)(k + 3) * Ddim];
            #pragma unroll
            for (int r = 0; r < MBLK; ++r) {
                float4 e = *(const float4*)&e_lds[r][k];
                acc[r] = fmaf(e.x, w0, acc[r]);
                acc[r] = fmaf(e.y, w1, acc[r]);
                acc[r] = fmaf(e.z, w2, acc[r]);
                acc[r] = fmaf(e.w, w3, acc[r]);
            }
        }
    }

    const float btj = (j < Ddim) ? bt[j] : 0.f;
    const float waj = (j < Ddim) ? Wa[j] : 0.f;
    const int wave = tid >> 6, lane = tid & 63;

    #pragma unroll
    for (int r = 0; r < MBLK; ++r) {
        float v = (j < Ddim) ? tanhf(acc[r] + btj) * waj : 0.f;
        #pragma unroll
        for (int off = 32; off > 0; off >>= 1) v += __shfl_xor(v, off, 64);
        if (lane == 0) ctx_lds[wave][r] = v;
    }
    __syncthreads();

    if (tid < MBLK) {
        float s = ba[0];
        #pragma unroll
        for (int w = 0; w < 5; ++w) s += ctx_lds[w][tid];
        scores[m0 + tid] = s;
    }
}

// ---------------------------------------------------------------------------
// Kernel B: softmax over the TIME axis, in place on the attn region.
// One wave per (b,p); elements at [b*T*P + t*P + p], t=0..199.
// ---------------------------------------------------------------------------
__global__ __launch_bounds__(64) void softmax_time_kernel(float* __restrict__ a)
{
    const int b = blockIdx.x / Pdim;
    const int p = blockIdx.x - b * Pdim;
    const int lane = threadIdx.x;
    const size_t base = (size_t)b * Tdim * Pdim + p;

    float v[4];
    float m = -1e30f;
    #pragma unroll
    for (int i = 0; i < 4; ++i) {
        int t = lane + i * 64;
        v[i] = (t < Tdim) ? a[base + (size_t)t * Pdim] : -1e30f;
        m = fmaxf(m, v[i]);
    }
    #pragma unroll
    for (int off = 32; off > 0; off >>= 1) m = fmaxf(m, __shfl_xor(m, off, 64));

    float s = 0.f;
    #pragma unroll
    for (int i = 0; i < 4; ++i) {
        int t = lane + i * 64;
        if (t < Tdim) { v[i] = expf(v[i] - m); s += v[i]; }
    }
    #pragma unroll
    for (int off = 32; off > 0; off >>= 1) s += __shfl_xor(s, off, 64);

    const float inv = 1.f / s;
    #pragma unroll
    for (int i = 0; i < 4; ++i) {
        int t = lane + i * 64;
        if (t < Tdim) a[base + (size_t)t * Pdim] = v[i] * inv;
    }
}

// ---------------------------------------------------------------------------
// Kernel C+D fused: per (b,t) block.
//   code_vec[c] = sum_p attn[b,t,p] * full_embed[b,t,p,c]   (re-gather)
//   kc = sigmoid(x@W_kc+b_kc); out = cv@W_skill+b_skill;
//   res2 = out * (z_kc>=0); res = sigmoid(res2@W_pred+b_pred)
// ---------------------------------------------------------------------------
__global__ __launch_bounds__(320) void cvpred_kernel(
    const float* __restrict__ x,
    const int*   __restrict__ c2v,
    const float* __restrict__ en,
    const float* __restrict__ ep,
    const float* __restrict__ attn,
    const float* __restrict__ Wsk, const float* __restrict__ bsk,
    const float* __restrict__ Wkc, const float* __restrict__ bkc,
    const float* __restrict__ Wpr, const float* __restrict__ bpr,
    float* __restrict__ res, float* __restrict__ res2, float* __restrict__ kcm)
{
    const int bt  = blockIdx.x;           // 0..B*T-1
    const int tid = threadIdx.x;

    __shared__ int   idx_lds[Pdim * 3];
    __shared__ float attn_lds[Pdim];
    __shared__ float x_lds[Qdim];
    __shared__ float cv_lds[Ddim];
    __shared__ float r2_lds[SKILL];

    if (tid < Pdim * 3) idx_lds[tid] = c2v[(size_t)bt * (Pdim * 3) + tid];
    if (tid < Pdim)     attn_lds[tid] = attn[(size_t)bt * Pdim + tid];
    if (tid < Qdim)     x_lds[tid] = x[(size_t)bt * Qdim + tid];
    __syncthreads();

    if (tid < Ddim) {
        const int seg = tid / 100, c = tid - seg * 100;
        float acc = 0.f;
        for (int p = 0; p < Pdim; ++p) {
            int i;
            const float* tab;
            if (seg == 0)      { i = idx_lds[p * 3 + 0]; tab = en; }
            else if (seg == 1) { i = idx_lds[p * 3 + 2]; tab = en; }
            else               { i = idx_lds[p * 3 + 1]; tab = ep; }
            acc = fmaf(attn_lds[p], tab[(size_t)i * EMB + c], acc);
        }
        cv_lds[tid] = acc;
    }
    __syncthreads();

    if (tid < SKILL) {
        const int s = tid;
        float zk = bkc[s];
        for (int q = 0; q < Qdim; ++q) zk = fmaf(x_lds[q], Wkc[q * SKILL + s], zk);
        float kc = 1.f / (1.f + expf(-zk));
        float o = bsk[s];
        for (int c = 0; c < Ddim; ++c) o = fmaf(cv_lds[c], Wsk[c * SKILL + s], o);
        float r2 = (zk >= 0.f) ? o : 0.f;   // sigmoid(zk)>=0.5 <=> zk>=0
        kcm [(size_t)bt * SKILL + s] = kc;
        res2[(size_t)bt * SKILL + s] = r2;
        r2_lds[s] = r2;
    }
    __syncthreads();

    if (tid < OUTD) {
        float z = bpr[tid];
        #pragma unroll
        for (int s = 0; s < SKILL; ++s) z = fmaf(r2_lds[s], Wpr[s * OUTD + tid], z);
        res[(size_t)bt * OUTD + tid] = 1.f / (1.f + expf(-z));
    }
}

// ---------------------------------------------------------------------------
extern "C" void kernel_launch(void* const* d_in, const int* in_sizes, int n_in,
                              void* d_out, int out_size, void* d_ws, size_t ws_size,
                              hipStream_t stream)
{
    const float* x   = (const float*)d_in[0];
    const int*   c2v = (const int*)  d_in[1];
    const float* en  = (const float*)d_in[2];
    const float* ep  = (const float*)d_in[3];
    const float* Wt  = (const float*)d_in[4];
    const float* bt  = (const float*)d_in[5];
    const float* Wa  = (const float*)d_in[6];
    const float* ba  = (const float*)d_in[7];
    const float* Wsk = (const float*)d_in[8];
    const float* bsk = (const float*)d_in[9];
    const float* Wkc = (const float*)d_in[10];
    const float* bkc = (const float*)d_in[11];
    const float* Wpr = (const float*)d_in[12];
    const float* bpr = (const float*)d_in[13];

    float* out  = (float*)d_out;
    float* res  = out + OFF_RES;
    float* res2 = out + OFF_RES2;
    float* kcm  = out + OFF_KC;
    float* attn = out + OFF_ATTN;

    // A: raw scores into the attn output region
    score_kernel<<<(Bdim * Tdim * Pdim) / MBLK, TPB_A, 0, stream>>>(
        c2v, en, ep, Wt, bt, Wa, ba, attn);

    // B: softmax over time, in place
    softmax_time_kernel<<<Bdim * Pdim, 64, 0, stream>>>(attn);

    // C+D: code_vectors + heads
    cvpred_kernel<<<Bdim * Tdim, 320, 0, stream>>>(
        x, c2v, en, ep, attn, Wsk, bsk, Wkc, bkc, Wpr, bpr, res, res2, kcm);
}

// Round 2
// 845.693 us; speedup vs baseline: 2.6795x; 2.6795x over previous
//
#include <hip/hip_runtime.h>
#include <hip/hip_bf16.h>
#include <math.h>

#define Bdim 16
#define Tdim 200
#define Pdim 100
#define EMB  100
#define Ddim 300
#define SKILL 30
#define Qdim 50
#define OUTD 50

// d_out layout (floats), concatenated in reference return order:
// res [B,T,50], res2 [B,T,30], kc_mask [B,T,30], attn [B,T,P,1]
#define OFF_RES   0
#define OFF_RES2  (Bdim*Tdim*OUTD)              // 160000
#define OFF_KC    (OFF_RES2 + Bdim*Tdim*SKILL)  // 256000
#define OFF_ATTN  (OFF_KC + Bdim*Tdim*SKILL)    // 352000

typedef __bf16 bf16x8 __attribute__((ext_vector_type(8)));
typedef __bf16 bf16x4 __attribute__((ext_vector_type(4)));
typedef float  f32x4  __attribute__((ext_vector_type(4)));

// MFMA geometry for the score GEMM
#define BM    128          // rows per block
#define KPAD  320          // padded K (and padded N)
#define ASTR  328          // A row stride in bf16 (656 B -> bank rotation 4)
#define BSTR  40           // B row stride in bf16 (80 B  -> bank rotation 20)
#define TPB   512          // 8 waves

__device__ __forceinline__ float fast_tanh(float x) {
    // tanh(x) = 1 - 2/(exp(2x)+1); v_exp + v_rcp, saturates correctly at +-inf
    float t = __expf(2.0f * x);
    return 1.0f - 2.0f * __builtin_amdgcn_rcpf(t + 1.0f);
}

// ---------------------------------------------------------------------------
// Prep: W_trans (300x300 fp32, row-major [k][j]) -> bf16 TRANSPOSED padded
// wbt[j][k], j,k in [0,320), zeros outside 300. 204800 B in d_ws.
// ---------------------------------------------------------------------------
__global__ __launch_bounds__(256) void prep_wbt_kernel(
    const float* __restrict__ Wt, __bf16* __restrict__ wbt)
{
    int id = blockIdx.x * 256 + threadIdx.x;
    if (id >= KPAD * KPAD) return;
    int j = id / KPAD, k = id - j * KPAD;
    float v = (j < Ddim && k < Ddim) ? Wt[k * Ddim + j] : 0.0f;
    wbt[id] = (__bf16)v;
}

// ---------------------------------------------------------------------------
// Kernel A (MFMA): raw attention scores.
// score[m] = tanh(E[m] @ W_trans + b_trans) @ W_att + b_att
// E[m] = [nodes[i0] | nodes[i2] | paths[i1]]  (concat order!)
// Block: 128 rows, 8 waves (2M x 4N). Wave tile: 64 rows x 80 cols
// = 4x5 mfma_f32_16x16x32_bf16 frags, K padded to 320 (10 k-tiles of 32).
// ---------------------------------------------------------------------------
__global__ __launch_bounds__(TPB, 2) void score_mfma_kernel(
    const int*    __restrict__ c2v,
    const float*  __restrict__ en,
    const float*  __restrict__ ep,
    const __bf16* __restrict__ wbt,   // [320][320] transposed bf16 W_trans
    const float*  __restrict__ bt,
    const float*  __restrict__ wa,
    const float*  __restrict__ ba,
    float* __restrict__ scores)
{
    __shared__ __bf16 A_lds[BM * ASTR];           // 83968 B
    __shared__ __bf16 B_lds[2][KPAD * BSTR];      // 2 x 25600 B
    __shared__ int    idx_lds[BM * 3];
    __shared__ float  red_lds[4][BM];             // 2048 B

    const int tid = threadIdx.x;
    const int m0  = blockIdx.x * BM;

    for (int i = tid; i < BM * 3; i += TPB) idx_lds[i] = c2v[(size_t)m0 * 3 + i];
    __syncthreads();

    // ---- stage A: gather fp32 embeddings, convert to bf16 ----
    for (int pos = tid; pos < BM * 75; pos += TPB) {
        int r = pos / 75, q = pos - r * 75;
        int seg = q / 25, qq = q - seg * 25;
        int i0 = idx_lds[r * 3 + 0];
        int i1 = idx_lds[r * 3 + 1];
        int i2 = idx_lds[r * 3 + 2];
        const float* src = (seg == 0) ? en + (size_t)i0 * EMB
                         : (seg == 1) ? en + (size_t)i2 * EMB
                                      : ep + (size_t)i1 * EMB;
        float4 v = ((const float4*)src)[qq];
        bf16x4 b4 = { (__bf16)v.x, (__bf16)v.y, (__bf16)v.z, (__bf16)v.w };
        *(bf16x4*)&A_lds[r * ASTR + seg * 100 + qq * 4] = b4;
    }
    // zero K-pad cols 300..319 (read by last k-tile)
    {
        bf16x4 z4 = { (__bf16)0.f, (__bf16)0.f, (__bf16)0.f, (__bf16)0.f };
        for (int pos = tid; pos < BM * 5; pos += TPB) {
            int r = pos / 5, q = pos - r * 5;
            *(bf16x4*)&A_lds[r * ASTR + 300 + q * 4] = z4;
        }
    }

    // ---- B staging helper (20 KB per k-tile) ----
    auto stageB = [&](int kt, int bsel) {
        const int k0 = kt * 32;
        for (int pos = tid; pos < KPAD * 4; pos += TPB) {
            int j = pos >> 2, ck = pos & 3;
            bf16x8 v = *(const bf16x8*)&wbt[j * KPAD + k0 + ck * 8];
            *(bf16x8*)&B_lds[bsel][j * BSTR + ck * 8] = v;
        }
    };

    stageB(0, 0);
    __syncthreads();

    const int wid = tid >> 6, lane = tid & 63;
    const int wm = wid >> 2, wn = wid & 3;       // 2 x 4 wave grid
    const int lr = lane & 15, lg = lane >> 4;

    f32x4 acc[4][5];
    #pragma unroll
    for (int mf = 0; mf < 4; ++mf)
        #pragma unroll
        for (int nf = 0; nf < 5; ++nf) acc[mf][nf] = (f32x4){0.f, 0.f, 0.f, 0.f};

    int buf = 0;
    for (int kt = 0; kt < 10; ++kt) {
        if (kt < 9) stageB(kt + 1, buf ^ 1);
        const int k0 = kt * 32;
        bf16x8 af[4], bfr[5];
        #pragma unroll
        for (int mf = 0; mf < 4; ++mf)
            af[mf] = *(const bf16x8*)&A_lds[(wm * 64 + mf * 16 + lr) * ASTR + k0 + lg * 8];
        #pragma unroll
        for (int nf = 0; nf < 5; ++nf)
            bfr[nf] = *(const bf16x8*)&B_lds[buf][(wn * 80 + nf * 16 + lr) * BSTR + lg * 8];
        #pragma unroll
        for (int mf = 0; mf < 4; ++mf)
            #pragma unroll
            for (int nf = 0; nf < 5; ++nf)
                acc[mf][nf] = __builtin_amdgcn_mfma_f32_16x16x32_bf16(
                    af[mf], bfr[nf], acc[mf][nf], 0, 0, 0);
        __syncthreads();
        buf ^= 1;
    }

    // ---- epilogue: tanh * W_att, reduce over columns ----
    float btv[5], wav[5];
    #pragma unroll
    for (int nf = 0; nf < 5; ++nf) {
        int c = wn * 80 + nf * 16 + lr;
        bool ok = (c < Ddim);
        btv[nf] = ok ? bt[c] : 0.f;
        wav[nf] = ok ? wa[c] : 0.f;
    }
    #pragma unroll
    for (int mf = 0; mf < 4; ++mf) {
        #pragma unroll
        for (int i = 0; i < 4; ++i) {
            float s = 0.f;
            #pragma unroll
            for (int nf = 0; nf < 5; ++nf)
                s += fast_tanh(acc[mf][nf][i] + btv[nf]) * wav[nf];
            // reduce across the 16-lane column dimension (lane bits 0..3)
            s += __shfl_xor(s, 1, 64);
            s += __shfl_xor(s, 2, 64);
            s += __shfl_xor(s, 4, 64);
            s += __shfl_xor(s, 8, 64);
            if (lr == 0) {
                int r = wm * 64 + mf * 16 + lg * 4 + i;
                red_lds[wn][r] = s;
            }
        }
    }
    __syncthreads();
    for (int r = tid; r < BM; r += TPB) {
        float s = ba[0] + red_lds[0][r] + red_lds[1][r] + red_lds[2][r] + red_lds[3][r];
        scores[m0 + r] = s;
    }
}

// ---------------------------------------------------------------------------
// Kernel B: softmax over the TIME axis, in place on the attn region.
// ---------------------------------------------------------------------------
__global__ __launch_bounds__(64) void softmax_time_kernel(float* __restrict__ a)
{
    const int b = blockIdx.x / Pdim;
    const int p = blockIdx.x - b * Pdim;
    const int lane = threadIdx.x;
    const size_t base = (size_t)b * Tdim * Pdim + p;

    float v[4];
    float m = -1e30f;
    #pragma unroll
    for (int i = 0; i < 4; ++i) {
        int t = lane + i * 64;
        v[i] = (t < Tdim) ? a[base + (size_t)t * Pdim] : -1e30f;
        m = fmaxf(m, v[i]);
    }
    #pragma unroll
    for (int off = 32; off > 0; off >>= 1) m = fmaxf(m, __shfl_xor(m, off, 64));

    float s = 0.f;
    #pragma unroll
    for (int i = 0; i < 4; ++i) {
        int t = lane + i * 64;
        if (t < Tdim) { v[i] = expf(v[i] - m); s += v[i]; }
    }
    #pragma unroll
    for (int off = 32; off > 0; off >>= 1) s += __shfl_xor(s, off, 64);

    const float inv = 1.f / s;
    #pragma unroll
    for (int i = 0; i < 4; ++i) {
        int t = lane + i * 64;
        if (t < Tdim) a[base + (size_t)t * Pdim] = v[i] * inv;
    }
}

// ---------------------------------------------------------------------------
// Kernel C+D fused: per (b,t) block.
//   code_vec[c] = sum_p attn[p] * full_embed[p][c]  (float4 re-gather)
//   kc = sigmoid(x@W_kc+b_kc); out = cv@W_skill+b_skill;
//   res2 = out * (z_kc>=0); res = sigmoid(res2@W_pred+b_pred)
// ---------------------------------------------------------------------------
__global__ __launch_bounds__(320) void cvpred_kernel(
    const float* __restrict__ x,
    const int*   __restrict__ c2v,
    const float* __restrict__ en,
    const float* __restrict__ ep,
    const float* __restrict__ attn,
    const float* __restrict__ Wsk, const float* __restrict__ bsk,
    const float* __restrict__ Wkc, const float* __restrict__ bkc,
    const float* __restrict__ Wpr, const float* __restrict__ bpr,
    float* __restrict__ res, float* __restrict__ res2, float* __restrict__ kcm)
{
    const int bt_i = blockIdx.x;           // 0..B*T-1
    const int tid  = threadIdx.x;

    __shared__ int    idx_lds[Pdim * 3];
    __shared__ float  attn_lds[Pdim];
    __shared__ float  x_lds[Qdim];
    __shared__ float4 part_lds[4][76];
    __shared__ float  cv_lds[Ddim];
    __shared__ float  r2_lds[SKILL];

    if (tid < Pdim * 3) idx_lds[tid] = c2v[(size_t)bt_i * (Pdim * 3) + tid];
    if (tid < Pdim)     attn_lds[tid] = attn[(size_t)bt_i * Pdim + tid];
    if (tid < Qdim)     x_lds[tid] = x[(size_t)bt_i * Qdim + tid];
    __syncthreads();

    // gather: 75 float4 chunk-columns x 4 p-groups
    {
        int pg = tid / 80, ch = tid - pg * 80;
        if (ch < 75) {
            int seg = ch / 25, cq = ch - seg * 25;
            const float* tab = (seg == 2) ? ep : en;
            int io = (seg == 0) ? 0 : (seg == 1) ? 2 : 1;
            float4 acc = {0.f, 0.f, 0.f, 0.f};
            for (int p = pg; p < Pdim; p += 4) {
                int i = idx_lds[p * 3 + io];
                float a = attn_lds[p];
                float4 v = *(const float4*)&tab[(size_t)i * EMB + cq * 4];
                acc.x = fmaf(a, v.x, acc.x);
                acc.y = fmaf(a, v.y, acc.y);
                acc.z = fmaf(a, v.z, acc.z);
                acc.w = fmaf(a, v.w, acc.w);
            }
            part_lds[pg][ch] = acc;
        }
    }
    __syncthreads();
    if (tid < 75) {
        float4 a0 = part_lds[0][tid], a1 = part_lds[1][tid];
        float4 a2 = part_lds[2][tid], a3 = part_lds[3][tid];
        int seg = tid / 25, cq = tid - seg * 25;
        int c = seg * 100 + cq * 4;
        cv_lds[c + 0] = a0.x + a1.x + a2.x + a3.x;
        cv_lds[c + 1] = a0.y + a1.y + a2.y + a3.y;
        cv_lds[c + 2] = a0.z + a1.z + a2.z + a3.z;
        cv_lds[c + 3] = a0.w + a1.w + a2.w + a3.w;
    }
    __syncthreads();

    if (tid < SKILL) {
        const int s = tid;
        float zk = bkc[s];
        for (int q = 0; q < Qdim; ++q) zk = fmaf(x_lds[q], Wkc[q * SKILL + s], zk);
        float kc = 1.f / (1.f + expf(-zk));
        float o = bsk[s];
        for (int c = 0; c < Ddim; ++c) o = fmaf(cv_lds[c], Wsk[c * SKILL + s], o);
        float r2 = (zk >= 0.f) ? o : 0.f;   // sigmoid(zk)>=0.5 <=> zk>=0
        kcm [(size_t)bt_i * SKILL + s] = kc;
        res2[(size_t)bt_i * SKILL + s] = r2;
        r2_lds[s] = r2;
    }
    __syncthreads();

    if (tid < OUTD) {
        float z = bpr[tid];
        #pragma unroll
        for (int s = 0; s < SKILL; ++s) z = fmaf(r2_lds[s], Wpr[s * OUTD + tid], z);
        res[(size_t)bt_i * OUTD + tid] = 1.f / (1.f + expf(-z));
    }
}

// ---------------------------------------------------------------------------
extern "C" void kernel_launch(void* const* d_in, const int* in_sizes, int n_in,
                              void* d_out, int out_size, void* d_ws, size_t ws_size,
                              hipStream_t stream)
{
    const float* x   = (const float*)d_in[0];
    const int*   c2v = (const int*)  d_in[1];
    const float* en  = (const float*)d_in[2];
    const float* ep  = (const float*)d_in[3];
    const float* Wt  = (const float*)d_in[4];
    const float* bt  = (const float*)d_in[5];
    const float* Wa  = (const float*)d_in[6];
    const float* ba  = (const float*)d_in[7];
    const float* Wsk = (const float*)d_in[8];
    const float* bsk = (const float*)d_in[9];
    const float* Wkc = (const float*)d_in[10];
    const float* bkc = (const float*)d_in[11];
    const float* Wpr = (const float*)d_in[12];
    const float* bpr = (const float*)d_in[13];

    float* out  = (float*)d_out;
    float* res  = out + OFF_RES;
    float* res2 = out + OFF_RES2;
    float* kcm  = out + OFF_KC;
    float* attn = out + OFF_ATTN;

    __bf16* wbt = (__bf16*)d_ws;   // 320*320*2 = 204800 B

    // P: W_trans -> bf16 transposed padded
    prep_wbt_kernel<<<(KPAD * KPAD + 255) / 256, 256, 0, stream>>>(Wt, wbt);

    // A: raw scores into the attn output region (MFMA)
    score_mfma_kernel<<<(Bdim * Tdim * Pdim) / BM, TPB, 0, stream>>>(
        c2v, en, ep, wbt, bt, Wa, ba, attn);

    // B: softmax over time, in place
    softmax_time_kernel<<<Bdim * Pdim, 64, 0, stream>>>(attn);

    // C+D: code_vectors + heads
    cvpred_kernel<<<Bdim * Tdim, 320, 0, stream>>>(
        x, c2v, en, ep, attn, Wsk, bsk, Wkc, bkc, Wpr, bpr, res, res2, kcm);
}

// Round 3
// 721.281 us; speedup vs baseline: 3.1416x; 1.1725x over previous
//
#include <hip/hip_runtime.h>
#include <hip/hip_bf16.h>
#include <math.h>

#define Bdim 16
#define Tdim 200
#define Pdim 100
#define EMB  100
#define Ddim 300
#define SKILL 30
#define Qdim 50
#define OUTD 50

// d_out layout (floats), concatenated in reference return order:
// res [B,T,50], res2 [B,T,30], kc_mask [B,T,30], attn [B,T,P,1]
#define OFF_RES   0
#define OFF_RES2  (Bdim*Tdim*OUTD)              // 160000
#define OFF_KC    (OFF_RES2 + Bdim*Tdim*SKILL)  // 256000
#define OFF_ATTN  (OFF_KC + Bdim*Tdim*SKILL)    // 352000

typedef __bf16 bf16x8 __attribute__((ext_vector_type(8)));
typedef __bf16 bf16x4 __attribute__((ext_vector_type(4)));
typedef float  f32x4  __attribute__((ext_vector_type(4)));

// MFMA geometry for the score GEMM
#define BM    128          // rows per block
#define KPAD  320          // padded K (and padded N)
#define ASTR  328          // A row stride in bf16 (656 B -> bank rotation 4)
#define BSTR  40           // B row stride in bf16 (80 B  -> bank rotation 20)
#define TPB   512          // 8 waves

#define NROWS (Bdim*Tdim*Pdim)                  // 320000
#define WBT_BYTES ((size_t)KPAD*KPAD*2)         // 204800
#define E_BYTES   ((size_t)NROWS*Ddim*2)        // 192,000,000

__device__ __forceinline__ float fast_tanh(float x) {
    // tanh(x) = 1 - 2/(exp(2x)+1); v_exp + v_rcp, saturates correctly at +-inf
    float t = __expf(2.0f * x);
    return 1.0f - 2.0f * __builtin_amdgcn_rcpf(t + 1.0f);
}

// ---------------------------------------------------------------------------
// Prep: W_trans (300x300 fp32, row-major [k][j]) -> bf16 TRANSPOSED padded
// wbt[j][k], j,k in [0,320), zeros outside 300. 204800 B in d_ws.
// ---------------------------------------------------------------------------
__global__ __launch_bounds__(256) void prep_wbt_kernel(
    const float* __restrict__ Wt, __bf16* __restrict__ wbt)
{
    int id = blockIdx.x * 256 + threadIdx.x;
    if (id >= KPAD * KPAD) return;
    int j = id / KPAD, k = id - j * KPAD;
    float v = (j < Ddim && k < Ddim) ? Wt[k * Ddim + j] : 0.0f;
    wbt[id] = (__bf16)v;
}

// ---------------------------------------------------------------------------
// Kernel A (MFMA): raw attention scores.
// score[m] = tanh(E[m] @ W_trans + b_trans) @ W_att + b_att
// E[m] = [nodes[i0] | nodes[i2] | paths[i1]]  (concat order!)
// Block: 128 rows, 8 waves (2M x 4N). Wave tile: 64 rows x 80 cols
// = 4x5 mfma_f32_16x16x32_bf16 frags, K padded to 320 (10 k-tiles of 32).
// If WRITE_E: also spill the gathered bf16 E tile linearly to e_out[m][300]
// so the downstream code-vector kernel can stream it instead of gathering.
// ---------------------------------------------------------------------------
template <bool WRITE_E>
__global__ __launch_bounds__(TPB, 2) void score_mfma_kernel(
    const int*    __restrict__ c2v,
    const float*  __restrict__ en,
    const float*  __restrict__ ep,
    const __bf16* __restrict__ wbt,   // [320][320] transposed bf16 W_trans
    const float*  __restrict__ bt,
    const float*  __restrict__ wa,
    const float*  __restrict__ ba,
    float* __restrict__ scores,
    __bf16* __restrict__ e_out)
{
    __shared__ __bf16 A_lds[BM * ASTR];           // 83968 B
    __shared__ __bf16 B_lds[2][KPAD * BSTR];      // 2 x 25600 B
    __shared__ int    idx_lds[BM * 3];
    __shared__ float  red_lds[4][BM];             // 2048 B

    const int tid = threadIdx.x;
    const int m0  = blockIdx.x * BM;

    for (int i = tid; i < BM * 3; i += TPB) idx_lds[i] = c2v[(size_t)m0 * 3 + i];
    __syncthreads();

    // ---- stage A: gather fp32 embeddings, convert to bf16 ----
    for (int pos = tid; pos < BM * 75; pos += TPB) {
        int r = pos / 75, q = pos - r * 75;
        int seg = q / 25, qq = q - seg * 25;
        int i0 = idx_lds[r * 3 + 0];
        int i1 = idx_lds[r * 3 + 1];
        int i2 = idx_lds[r * 3 + 2];
        const float* src = (seg == 0) ? en + (size_t)i0 * EMB
                         : (seg == 1) ? en + (size_t)i2 * EMB
                                      : ep + (size_t)i1 * EMB;
        float4 v = ((const float4*)src)[qq];
        bf16x4 b4 = { (__bf16)v.x, (__bf16)v.y, (__bf16)v.z, (__bf16)v.w };
        *(bf16x4*)&A_lds[r * ASTR + seg * 100 + qq * 4] = b4;
    }
    // zero K-pad cols 300..319 (read by last k-tile)
    {
        bf16x4 z4 = { (__bf16)0.f, (__bf16)0.f, (__bf16)0.f, (__bf16)0.f };
        for (int pos = tid; pos < BM * 5; pos += TPB) {
            int r = pos / 5, q = pos - r * 5;
            *(bf16x4*)&A_lds[r * ASTR + 300 + q * 4] = z4;
        }
    }

    // ---- B staging helper (20 KB per k-tile) ----
    auto stageB = [&](int kt, int bsel) {
        const int k0 = kt * 32;
        for (int pos = tid; pos < KPAD * 4; pos += TPB) {
            int j = pos >> 2, ck = pos & 3;
            bf16x8 v = *(const bf16x8*)&wbt[j * KPAD + k0 + ck * 8];
            *(bf16x8*)&B_lds[bsel][j * BSTR + ck * 8] = v;
        }
    };

    stageB(0, 0);
    __syncthreads();

    // ---- spill bf16 E tile linearly for the code-vector kernel ----
    if (WRITE_E) {
        for (int pos = tid; pos < BM * 75; pos += TPB) {
            int r = pos / 75, q = pos - r * 75;
            bf16x4 v = *(const bf16x4*)&A_lds[r * ASTR + q * 4];
            *(bf16x4*)&e_out[(size_t)(m0 + r) * Ddim + q * 4] = v;
        }
    }

    const int wid = tid >> 6, lane = tid & 63;
    const int wm = wid >> 2, wn = wid & 3;       // 2 x 4 wave grid
    const int lr = lane & 15, lg = lane >> 4;

    f32x4 acc[4][5];
    #pragma unroll
    for (int mf = 0; mf < 4; ++mf)
        #pragma unroll
        for (int nf = 0; nf < 5; ++nf) acc[mf][nf] = (f32x4){0.f, 0.f, 0.f, 0.f};

    int buf = 0;
    for (int kt = 0; kt < 10; ++kt) {
        if (kt < 9) stageB(kt + 1, buf ^ 1);
        const int k0 = kt * 32;
        bf16x8 af[4], bfr[5];
        #pragma unroll
        for (int mf = 0; mf < 4; ++mf)
            af[mf] = *(const bf16x8*)&A_lds[(wm * 64 + mf * 16 + lr) * ASTR + k0 + lg * 8];
        #pragma unroll
        for (int nf = 0; nf < 5; ++nf)
            bfr[nf] = *(const bf16x8*)&B_lds[buf][(wn * 80 + nf * 16 + lr) * BSTR + lg * 8];
        #pragma unroll
        for (int mf = 0; mf < 4; ++mf)
            #pragma unroll
            for (int nf = 0; nf < 5; ++nf)
                acc[mf][nf] = __builtin_amdgcn_mfma_f32_16x16x32_bf16(
                    af[mf], bfr[nf], acc[mf][nf], 0, 0, 0);
        __syncthreads();
        buf ^= 1;
    }

    // ---- epilogue: tanh * W_att, reduce over columns ----
    float btv[5], wav[5];
    #pragma unroll
    for (int nf = 0; nf < 5; ++nf) {
        int c = wn * 80 + nf * 16 + lr;
        bool ok = (c < Ddim);
        btv[nf] = ok ? bt[c] : 0.f;
        wav[nf] = ok ? wa[c] : 0.f;
    }
    #pragma unroll
    for (int mf = 0; mf < 4; ++mf) {
        #pragma unroll
        for (int i = 0; i < 4; ++i) {
            float s = 0.f;
            #pragma unroll
            for (int nf = 0; nf < 5; ++nf)
                s += fast_tanh(acc[mf][nf][i] + btv[nf]) * wav[nf];
            // reduce across the 16-lane column dimension (lane bits 0..3)
            s += __shfl_xor(s, 1, 64);
            s += __shfl_xor(s, 2, 64);
            s += __shfl_xor(s, 4, 64);
            s += __shfl_xor(s, 8, 64);
            if (lr == 0) {
                int r = wm * 64 + mf * 16 + lg * 4 + i;
                red_lds[wn][r] = s;
            }
        }
    }
    __syncthreads();
    for (int r = tid; r < BM; r += TPB) {
        float s = ba[0] + red_lds[0][r] + red_lds[1][r] + red_lds[2][r] + red_lds[3][r];
        scores[m0 + r] = s;
    }
}

// ---------------------------------------------------------------------------
// Kernel B: softmax over the TIME axis, in place on the attn region.
// ---------------------------------------------------------------------------
__global__ __launch_bounds__(64) void softmax_time_kernel(float* __restrict__ a)
{
    const int b = blockIdx.x / Pdim;
    const int p = blockIdx.x - b * Pdim;
    const int lane = threadIdx.x;
    const size_t base = (size_t)b * Tdim * Pdim + p;

    float v[4];
    float m = -1e30f;
    #pragma unroll
    for (int i = 0; i < 4; ++i) {
        int t = lane + i * 64;
        v[i] = (t < Tdim) ? a[base + (size_t)t * Pdim] : -1e30f;
        m = fmaxf(m, v[i]);
    }
    #pragma unroll
    for (int off = 32; off > 0; off >>= 1) m = fmaxf(m, __shfl_xor(m, off, 64));

    float s = 0.f;
    #pragma unroll
    for (int i = 0; i < 4; ++i) {
        int t = lane + i * 64;
        if (t < Tdim) { v[i] = expf(v[i] - m); s += v[i]; }
    }
    #pragma unroll
    for (int off = 32; off > 0; off >>= 1) s += __shfl_xor(s, off, 64);

    const float inv = 1.f / s;
    #pragma unroll
    for (int i = 0; i < 4; ++i) {
        int t = lane + i * 64;
        if (t < Tdim) a[base + (size_t)t * Pdim] = v[i] * inv;
    }
}

// ---------------------------------------------------------------------------
// Kernel C+D v2: per (b,t) block, STREAMS bf16 E rows from ws (no gather).
//   code_vec[c] = sum_p attn[p] * E[bt*100+p][c]
//   kc = sigmoid(x@W_kc+b_kc); out = cv@W_skill+b_skill;
//   res2 = out * (z_kc>=0); res = sigmoid(res2@W_pred+b_pred)
// 512 threads: pg = tid>>7 (4 p-groups), ch = tid&127 (75 active float4-chunks)
// ---------------------------------------------------------------------------
__global__ __launch_bounds__(512) void cvpred2_kernel(
    const float*  __restrict__ x,
    const __bf16* __restrict__ E,
    const float*  __restrict__ attn,
    const float* __restrict__ Wsk, const float* __restrict__ bsk,
    const float* __restrict__ Wkc, const float* __restrict__ bkc,
    const float* __restrict__ Wpr, const float* __restrict__ bpr,
    float* __restrict__ res, float* __restrict__ res2, float* __restrict__ kcm)
{
    const int bt_i = blockIdx.x;           // 0..B*T-1
    const int tid  = threadIdx.x;

    __shared__ float  attn_lds[Pdim];
    __shared__ float  x_lds[Qdim];
    __shared__ float4 part_lds[4][76];
    __shared__ float  cv_lds[Ddim];
    __shared__ float  r2_lds[SKILL];

    if (tid < Pdim) attn_lds[tid] = attn[(size_t)bt_i * Pdim + tid];
    if (tid >= 256 && tid < 256 + Qdim) x_lds[tid - 256] = x[(size_t)bt_i * Qdim + tid - 256];
    __syncthreads();

    const int pg = tid >> 7, ch = tid & 127;
    if (ch < 75) {
        const __bf16* base = E + (size_t)bt_i * (Pdim * Ddim) + ch * 4;
        float4 acc = {0.f, 0.f, 0.f, 0.f};
        #pragma unroll
        for (int p = pg; p < Pdim; p += 4) {
            bf16x4 v = *(const bf16x4*)(base + p * Ddim);
            float a = attn_lds[p];
            acc.x = fmaf(a, (float)v.x, acc.x);
            acc.y = fmaf(a, (float)v.y, acc.y);
            acc.z = fmaf(a, (float)v.z, acc.z);
            acc.w = fmaf(a, (float)v.w, acc.w);
        }
        part_lds[pg][ch] = acc;
    }
    __syncthreads();
    if (tid < 75) {
        float4 a0 = part_lds[0][tid], a1 = part_lds[1][tid];
        float4 a2 = part_lds[2][tid], a3 = part_lds[3][tid];
        int c = tid * 4;
        cv_lds[c + 0] = a0.x + a1.x + a2.x + a3.x;
        cv_lds[c + 1] = a0.y + a1.y + a2.y + a3.y;
        cv_lds[c + 2] = a0.z + a1.z + a2.z + a3.z;
        cv_lds[c + 3] = a0.w + a1.w + a2.w + a3.w;
    }
    __syncthreads();

    if (tid < SKILL) {
        const int s = tid;
        float zk = bkc[s];
        for (int q = 0; q < Qdim; ++q) zk = fmaf(x_lds[q], Wkc[q * SKILL + s], zk);
        float kc = 1.f / (1.f + expf(-zk));
        float o = bsk[s];
        for (int c = 0; c < Ddim; ++c) o = fmaf(cv_lds[c], Wsk[c * SKILL + s], o);
        float r2 = (zk >= 0.f) ? o : 0.f;   // sigmoid(zk)>=0.5 <=> zk>=0
        kcm [(size_t)bt_i * SKILL + s] = kc;
        res2[(size_t)bt_i * SKILL + s] = r2;
        r2_lds[s] = r2;
    }
    __syncthreads();

    if (tid < OUTD) {
        float z = bpr[tid];
        #pragma unroll
        for (int s = 0; s < SKILL; ++s) z = fmaf(r2_lds[s], Wpr[s * OUTD + tid], z);
        res[(size_t)bt_i * OUTD + tid] = 1.f / (1.f + expf(-z));
    }
}

// ---------------------------------------------------------------------------
// Fallback kernel C+D (gather version) if ws is too small for the E spill.
// ---------------------------------------------------------------------------
__global__ __launch_bounds__(320) void cvpred_kernel(
    const float* __restrict__ x,
    const int*   __restrict__ c2v,
    const float* __restrict__ en,
    const float* __restrict__ ep,
    const float* __restrict__ attn,
    const float* __restrict__ Wsk, const float* __restrict__ bsk,
    const float* __restrict__ Wkc, const float* __restrict__ bkc,
    const float* __restrict__ Wpr, const float* __restrict__ bpr,
    float* __restrict__ res, float* __restrict__ res2, float* __restrict__ kcm)
{
    const int bt_i = blockIdx.x;           // 0..B*T-1
    const int tid  = threadIdx.x;

    __shared__ int    idx_lds[Pdim * 3];
    __shared__ float  attn_lds[Pdim];
    __shared__ float  x_lds[Qdim];
    __shared__ float4 part_lds[4][76];
    __shared__ float  cv_lds[Ddim];
    __shared__ float  r2_lds[SKILL];

    if (tid < Pdim * 3) idx_lds[tid] = c2v[(size_t)bt_i * (Pdim * 3) + tid];
    if (tid < Pdim)     attn_lds[tid] = attn[(size_t)bt_i * Pdim + tid];
    if (tid < Qdim)     x_lds[tid] = x[(size_t)bt_i * Qdim + tid];
    __syncthreads();

    {
        int pg = tid / 80, ch = tid - pg * 80;
        if (ch < 75) {
            int seg = ch / 25, cq = ch - seg * 25;
            const float* tab = (seg == 2) ? ep : en;
            int io = (seg == 0) ? 0 : (seg == 1) ? 2 : 1;
            float4 acc = {0.f, 0.f, 0.f, 0.f};
            for (int p = pg; p < Pdim; p += 4) {
                int i = idx_lds[p * 3 + io];
                float a = attn_lds[p];
                float4 v = *(const float4*)&tab[(size_t)i * EMB + cq * 4];
                acc.x = fmaf(a, v.x, acc.x);
                acc.y = fmaf(a, v.y, acc.y);
                acc.z = fmaf(a, v.z, acc.z);
                acc.w = fmaf(a, v.w, acc.w);
            }
            part_lds[pg][ch] = acc;
        }
    }
    __syncthreads();
    if (tid < 75) {
        float4 a0 = part_lds[0][tid], a1 = part_lds[1][tid];
        float4 a2 = part_lds[2][tid], a3 = part_lds[3][tid];
        int seg = tid / 25, cq = tid - seg * 25;
        int c = seg * 100 + cq * 4;
        cv_lds[c + 0] = a0.x + a1.x + a2.x + a3.x;
        cv_lds[c + 1] = a0.y + a1.y + a2.y + a3.y;
        cv_lds[c + 2] = a0.z + a1.z + a2.z + a3.z;
        cv_lds[c + 3] = a0.w + a1.w + a2.w + a3.w;
    }
    __syncthreads();

    if (tid < SKILL) {
        const int s = tid;
        float zk = bkc[s];
        for (int q = 0; q < Qdim; ++q) zk = fmaf(x_lds[q], Wkc[q * SKILL + s], zk);
        float kc = 1.f / (1.f + expf(-zk));
        float o = bsk[s];
        for (int c = 0; c < Ddim; ++c) o = fmaf(cv_lds[c], Wsk[c * SKILL + s], o);
        float r2 = (zk >= 0.f) ? o : 0.f;
        kcm [(size_t)bt_i * SKILL + s] = kc;
        res2[(size_t)bt_i * SKILL + s] = r2;
        r2_lds[s] = r2;
    }
    __syncthreads();

    if (tid < OUTD) {
        float z = bpr[tid];
        #pragma unroll
        for (int s = 0; s < SKILL; ++s) z = fmaf(r2_lds[s], Wpr[s * OUTD + tid], z);
        res[(size_t)bt_i * OUTD + tid] = 1.f / (1.f + expf(-z));
    }
}

// ---------------------------------------------------------------------------
extern "C" void kernel_launch(void* const* d_in, const int* in_sizes, int n_in,
                              void* d_out, int out_size, void* d_ws, size_t ws_size,
                              hipStream_t stream)
{
    const float* x   = (const float*)d_in[0];
    const int*   c2v = (const int*)  d_in[1];
    const float* en  = (const float*)d_in[2];
    const float* ep  = (const float*)d_in[3];
    const float* Wt  = (const float*)d_in[4];
    const float* bt  = (const float*)d_in[5];
    const float* Wa  = (const float*)d_in[6];
    const float* ba  = (const float*)d_in[7];
    const float* Wsk = (const float*)d_in[8];
    const float* bsk = (const float*)d_in[9];
    const float* Wkc = (const float*)d_in[10];
    const float* bkc = (const float*)d_in[11];
    const float* Wpr = (const float*)d_in[12];
    const float* bpr = (const float*)d_in[13];

    float* out  = (float*)d_out;
    float* res  = out + OFF_RES;
    float* res2 = out + OFF_RES2;
    float* kcm  = out + OFF_KC;
    float* attn = out + OFF_ATTN;

    __bf16* wbt  = (__bf16*)d_ws;                       // 204800 B
    __bf16* e_ws = (__bf16*)((char*)d_ws + WBT_BYTES);  // 192 MB bf16 E spill

    const bool use_e_spill = ws_size >= WBT_BYTES + E_BYTES;

    // P: W_trans -> bf16 transposed padded
    prep_wbt_kernel<<<(KPAD * KPAD + 255) / 256, 256, 0, stream>>>(Wt, wbt);

    // A: raw scores into the attn output region (MFMA), optional E spill
    if (use_e_spill)
        score_mfma_kernel<true><<<NROWS / BM, TPB, 0, stream>>>(
            c2v, en, ep, wbt, bt, Wa, ba, attn, e_ws);
    else
        score_mfma_kernel<false><<<NROWS / BM, TPB, 0, stream>>>(
            c2v, en, ep, wbt, bt, Wa, ba, attn, e_ws);

    // B: softmax over time, in place
    softmax_time_kernel<<<Bdim * Pdim, 64, 0, stream>>>(attn);

    // C+D: code_vectors + heads
    if (use_e_spill)
        cvpred2_kernel<<<Bdim * Tdim, 512, 0, stream>>>(
            x, e_ws, attn, Wsk, bsk, Wkc, bkc, Wpr, bpr, res, res2, kcm);
    else
        cvpred_kernel<<<Bdim * Tdim, 320, 0, stream>>>(
            x, c2v, en, ep, attn, Wsk, bsk, Wkc, bkc, Wpr, bpr, res, res2, kcm);
}